// Round 1
// baseline (138.789 us; speedup 1.0000x reference)
//
#include <hip/hip_runtime.h>
#include <math.h>

// B=65536, D=8, H=2 (hd=4), S=15 tokens (5+5+5), A=20 outputs.
// One token per thread, 16 threads/element (thread 15 idle in token phases),
// 16 elements per 256-thread block, grid = 65536/16 = 4096 blocks.
#define EPB 16
#define BTOT 65536

__device__ __forceinline__ float fast_exp2(float x) {
#if defined(__has_builtin)
#if __has_builtin(__builtin_amdgcn_exp2f)
  return __builtin_amdgcn_exp2f(x);
#else
  return exp2f(x);
#endif
#else
  return exp2f(x);
#endif
}

// kb/vb: [elem][token(pad to 17)][8]; element stride = 17*8 floats = 544 B
// -> per-wave the 4 element groups land on bank offsets {0,8,16,24}: conflict-free.
__device__ __forceinline__ void attn_layer(
    float x[8], int e, int t,
    const float* __restrict__ Wqkv, const float* __restrict__ bqkv,
    const float* __restrict__ Wo, const float* __restrict__ bo,
    const float* __restrict__ Wl, const float* __restrict__ bl,
    float (*kb)[17][8], float (*vb)[17][8])
{
  float q[8];
  if (t < 15) {
    float k[8], v[8];
#pragma unroll
    for (int c = 0; c < 8; ++c) {
      float aq = bqkv[c];
      float ak = bqkv[8 + c];
      float av = bqkv[16 + c];
#pragma unroll
      for (int j = 0; j < 8; ++j) {
        aq = fmaf(x[j], Wqkv[c * 8 + j], aq);
        ak = fmaf(x[j], Wqkv[(8 + c) * 8 + j], ak);
        av = fmaf(x[j], Wqkv[(16 + c) * 8 + j], av);
      }
      q[c] = aq; k[c] = ak; v[c] = av;
    }
    float4* kd = (float4*)kb[e][t];
    kd[0] = make_float4(k[0], k[1], k[2], k[3]);
    kd[1] = make_float4(k[4], k[5], k[6], k[7]);
    float4* vd = (float4*)vb[e][t];
    vd[0] = make_float4(v[0], v[1], v[2], v[3]);
    vd[1] = make_float4(v[4], v[5], v[6], v[7]);
  }
  __syncthreads();
  if (t < 15) {
    float s0[15], s1[15];
#pragma unroll
    for (int u = 0; u < 15; ++u) {
      const float4 k0 = *(const float4*)(kb[e][u]);
      const float4 k1 = *(const float4*)(kb[e][u] + 4);
      float a0 = q[0] * k0.x;
      a0 = fmaf(q[1], k0.y, a0); a0 = fmaf(q[2], k0.z, a0); a0 = fmaf(q[3], k0.w, a0);
      float a1 = q[4] * k1.x;
      a1 = fmaf(q[5], k1.y, a1); a1 = fmaf(q[6], k1.z, a1); a1 = fmaf(q[7], k1.w, a1);
      s0[u] = a0 * 0.5f;   // hd^-0.5 = 0.5
      s1[u] = a1 * 0.5f;
    }
    // softmax per head over the 15 keys
    float m0 = s0[0], m1 = s1[0];
#pragma unroll
    for (int u = 1; u < 15; ++u) { m0 = fmaxf(m0, s0[u]); m1 = fmaxf(m1, s1[u]); }
    float sum0 = 0.f, sum1 = 0.f;
#pragma unroll
    for (int u = 0; u < 15; ++u) {
      s0[u] = fast_exp2((s0[u] - m0) * 1.4426950408889634f);
      s1[u] = fast_exp2((s1[u] - m1) * 1.4426950408889634f);
      sum0 += s0[u]; sum1 += s1[u];
    }
    const float r0 = 1.0f / sum0, r1 = 1.0f / sum1;
    float o[8] = {0.f, 0.f, 0.f, 0.f, 0.f, 0.f, 0.f, 0.f};
#pragma unroll
    for (int u = 0; u < 15; ++u) {
      const float4 v0 = *(const float4*)(vb[e][u]);
      const float4 v1 = *(const float4*)(vb[e][u] + 4);
      o[0] = fmaf(s0[u], v0.x, o[0]); o[1] = fmaf(s0[u], v0.y, o[1]);
      o[2] = fmaf(s0[u], v0.z, o[2]); o[3] = fmaf(s0[u], v0.w, o[3]);
      o[4] = fmaf(s1[u], v1.x, o[4]); o[5] = fmaf(s1[u], v1.y, o[5]);
      o[6] = fmaf(s1[u], v1.z, o[6]); o[7] = fmaf(s1[u], v1.w, o[7]);
    }
#pragma unroll
    for (int d = 0; d < 4; ++d) { o[d] *= r0; o[4 + d] *= r1; }
    // x = x + o @ Wo.T + bo
    float xn[8];
#pragma unroll
    for (int c = 0; c < 8; ++c) {
      float acc = bo[c];
#pragma unroll
      for (int j = 0; j < 8; ++j) acc = fmaf(o[j], Wo[c * 8 + j], acc);
      xn[c] = x[c] + acc;
    }
    // x = xn + relu(xn @ Wl.T + bl)
#pragma unroll
    for (int c = 0; c < 8; ++c) {
      float acc = bl[c];
#pragma unroll
      for (int j = 0; j < 8; ++j) acc = fmaf(xn[j], Wl[c * 8 + j], acc);
      x[c] = xn[c] + fmaxf(acc, 0.0f);
    }
  }
  __syncthreads();  // protect kb/vb before next layer's writes
}

__global__ __launch_bounds__(256) void BetterBot_44169443672375_kernel(
    const int* __restrict__ dice_type, const int* __restrict__ dice_star,
    const int* __restrict__ summon_lvl,
    const float* __restrict__ emb_dice, const float* __restrict__ emb_star,
    const float* __restrict__ emb_btns,
    const float* __restrict__ Wout, const float* __restrict__ bout,
    const float* __restrict__ Wqkv0, const float* __restrict__ bqkv0,
    const float* __restrict__ Wo0, const float* __restrict__ bo0,
    const float* __restrict__ Wl0, const float* __restrict__ bl0,
    const float* __restrict__ Wqkv1, const float* __restrict__ bqkv1,
    const float* __restrict__ Wo1, const float* __restrict__ bo1,
    const float* __restrict__ Wl1, const float* __restrict__ bl1,
    float* __restrict__ out)
{
  __shared__ __align__(16) float kb[EPB][17][8];
  __shared__ __align__(16) float vb[EPB][17][8];
  const int tid = threadIdx.x;
  const int e = tid >> 4;          // element within block
  const int t = tid & 15;          // token (0..14 active)
  const int ge = blockIdx.x * EPB + e;

  float x[8];
  if (t < 15) {
    const float* row;
    if (t < 5)       row = emb_dice + 8 * dice_type[ge * 5 + t];
    else if (t < 10) row = emb_star + 8 * dice_star[ge * 5 + (t - 5)];
    else             row = emb_btns + 8 * summon_lvl[ge * 5 + (t - 10)];
    const float4 r0 = *(const float4*)row;
    const float4 r1 = *(const float4*)(row + 4);
    x[0] = r0.x; x[1] = r0.y; x[2] = r0.z; x[3] = r0.w;
    x[4] = r1.x; x[5] = r1.y; x[6] = r1.z; x[7] = r1.w;
  }

  attn_layer(x, e, t, Wqkv0, bqkv0, Wo0, bo0, Wl0, bl0, kb, vb);
  attn_layer(x, e, t, Wqkv1, bqkv1, Wo1, bo1, Wl1, bl1, kb, vb);

  // epilogue: mean over tokens, then [8] @ Wout.T[8,20] + bout
  if (t < 15) {
    float4* xd = (float4*)kb[e][t];
    xd[0] = make_float4(x[0], x[1], x[2], x[3]);
    xd[1] = make_float4(x[4], x[5], x[6], x[7]);
  }
  __syncthreads();
  if (t < 8) {
    float s = 0.f;
#pragma unroll
    for (int u = 0; u < 15; ++u) s += kb[e][u][t];
    vb[e][0][t] = s * (1.0f / 15.0f);
  }
  __syncthreads();
  const int obase = blockIdx.x * (EPB * 20);
  for (int idx = tid; idx < EPB * 20; idx += 256) {
    const int e2 = idx / 20;
    const int a = idx - e2 * 20;
    const float* mr = vb[e2][0];
    float acc = bout[a];
#pragma unroll
    for (int j = 0; j < 8; ++j) acc = fmaf(mr[j], Wout[a * 8 + j], acc);
    out[obase + idx] = acc;   // contiguous per block -> coalesced
  }
}

extern "C" void kernel_launch(void* const* d_in, const int* in_sizes, int n_in,
                              void* d_out, int out_size, void* d_ws, size_t ws_size,
                              hipStream_t stream) {
  const int*   dice_type  = (const int*)d_in[0];
  const int*   dice_star  = (const int*)d_in[1];
  const int*   summon_lvl = (const int*)d_in[2];
  const float* emb_dice   = (const float*)d_in[3];
  const float* emb_star   = (const float*)d_in[4];
  const float* emb_btns   = (const float*)d_in[5];
  const float* Wout       = (const float*)d_in[6];
  const float* bout       = (const float*)d_in[7];
  const float* Wqkv0      = (const float*)d_in[8];
  const float* bqkv0      = (const float*)d_in[9];
  const float* Wo0        = (const float*)d_in[10];
  const float* bo0        = (const float*)d_in[11];
  const float* Wl0        = (const float*)d_in[12];
  const float* bl0        = (const float*)d_in[13];
  const float* Wqkv1      = (const float*)d_in[14];
  const float* bqkv1      = (const float*)d_in[15];
  const float* Wo1        = (const float*)d_in[16];
  const float* bo1        = (const float*)d_in[17];
  const float* Wl1        = (const float*)d_in[18];
  const float* bl1        = (const float*)d_in[19];
  float* out = (float*)d_out;

  dim3 grid(BTOT / EPB), block(256);
  hipLaunchKernelGGL(BetterBot_44169443672375_kernel, grid, block, 0, stream,
                     dice_type, dice_star, summon_lvl,
                     emb_dice, emb_star, emb_btns, Wout, bout,
                     Wqkv0, bqkv0, Wo0, bo0, Wl0, bl0,
                     Wqkv1, bqkv1, Wo1, bo1, Wl1, bl1,
                     out);
}